// Round 5
// baseline (350.952 us; speedup 1.0000x reference)
//
#include <hip/hip_runtime.h>

typedef __bf16 bf16;
typedef bf16 bf16x8 __attribute__((ext_vector_type(8)));
typedef bf16 bf16x4 __attribute__((ext_vector_type(4)));
typedef float f32x4 __attribute__((ext_vector_type(4)));

#define MFMA16(a, b, c) __builtin_amdgcn_mfma_f32_16x16x32_bf16((a), (b), (c), 0, 0, 0)

__device__ __forceinline__ void gload_lds16(const bf16* g, bf16* l) {
  __builtin_amdgcn_global_load_lds(
      (const __attribute__((address_space(1))) void*)g,
      (__attribute__((address_space(3))) void*)l, 16, 0, 0);
}

// ---------------------------------------------------------------------------
// One fused fp32 -> bf16 convert for all 5 tensors (saves 4 launch gaps)
// ---------------------------------------------------------------------------
__global__ __launch_bounds__(256) void cvt_all(const float* __restrict__ hid,
                                               const float* __restrict__ Wq,
                                               const float* __restrict__ Wk,
                                               const float* __restrict__ Wv,
                                               const float* __restrict__ Wo,
                                               bf16* __restrict__ Xbf,
                                               bf16* __restrict__ Wcat,
                                               bf16* __restrict__ Wob) {
  int i = blockIdx.x * blockDim.x + threadIdx.x;  // 5242880 total float4s
  const float* s;
  bf16* d;
  if (i < 2097152)       { s = hid; d = Xbf; }
  else if (i < 3145728)  { i -= 2097152; s = Wq; d = Wcat; }
  else if (i < 3670016)  { i -= 3145728; s = Wk; d = Wcat + 4194304; }
  else if (i < 4194304)  { i -= 3670016; s = Wv; d = Wcat + 6291456; }
  else                   { i -= 4194304; s = Wo; d = Wob; }
  float4 v = ((const float4*)s)[i];
  bf16x4 o;
  o[0] = (bf16)v.x; o[1] = (bf16)v.y; o[2] = (bf16)v.z; o[3] = (bf16)v.w;
  ((bf16x4*)d)[i] = o;
}

// ---------------------------------------------------------------------------
// GEMM C = A * B^T (m97 structure). ldk = row stride; K = k-extent per z-slice
// (split-K via blockIdx.z: A/B advance z*K columns, C advances z*zcs elems).
// ---------------------------------------------------------------------------
template <typename OutT>
__global__ __launch_bounds__(256) void gemm_bt(const bf16* __restrict__ A,
                                               const bf16* __restrict__ B,
                                               OutT* __restrict__ C,
                                               int M, int N, int K, int ldk,
                                               size_t zcs) {
  __shared__ __align__(16) bf16 As[128 * 64];
  __shared__ __align__(16) bf16 Bs[128 * 64];
  A += (size_t)blockIdx.z * K;
  B += (size_t)blockIdx.z * K;
  C += (size_t)blockIdx.z * zcs;
  const int tid = threadIdx.x;
  const int w = tid >> 6, lane = tid & 63;
  const int l15 = lane & 15, quad = lane >> 4;
  const int m0 = blockIdx.y * 128, n0 = blockIdx.x * 128;
  const int wm = (w >> 1) * 64, wn = (w & 1) * 64;

  f32x4 acc[4][4] = {};

  for (int k0 = 0; k0 < K; k0 += 64) {
#pragma unroll
    for (int i = 0; i < 4; i++) {
      int s = w * 256 + i * 64 + lane;
      int row = s >> 3;
      int c8 = (s & 7) ^ (row & 7);
      gload_lds16(A + (size_t)(m0 + row) * ldk + k0 + c8 * 8, As + (w * 256 + i * 64) * 8);
    }
#pragma unroll
    for (int i = 0; i < 4; i++) {
      int s = w * 256 + i * 64 + lane;
      int row = s >> 3;
      int c8 = (s & 7) ^ (row & 7);
      gload_lds16(B + (size_t)(n0 + row) * ldk + k0 + c8 * 8, Bs + (w * 256 + i * 64) * 8);
    }
    __syncthreads();

#pragma unroll
    for (int kk = 0; kk < 2; kk++) {
      bf16x8 af[4], bfr[4];
#pragma unroll
      for (int mt = 0; mt < 4; mt++) {
        int row = wm + mt * 16 + l15;
        int slot = row * 8 + ((kk * 4 + quad) ^ (row & 7));
        af[mt] = *(const bf16x8*)(As + slot * 8);
      }
#pragma unroll
      for (int nt = 0; nt < 4; nt++) {
        int row = wn + nt * 16 + l15;
        int slot = row * 8 + ((kk * 4 + quad) ^ (row & 7));
        bfr[nt] = *(const bf16x8*)(Bs + slot * 8);
      }
#pragma unroll
      for (int mt = 0; mt < 4; mt++)
#pragma unroll
        for (int nt = 0; nt < 4; nt++)
          acc[mt][nt] = MFMA16(af[mt], bfr[nt], acc[mt][nt]);
    }
    __syncthreads();
  }

#pragma unroll
  for (int mt = 0; mt < 4; mt++)
#pragma unroll
    for (int nt = 0; nt < 4; nt++) {
      int row = m0 + wm + mt * 16 + quad * 4;
      int col = n0 + wn + nt * 16 + l15;
#pragma unroll
      for (int r = 0; r < 4; r++)
        C[(size_t)(row + r) * N + col] = (OutT)acc[mt][nt][r];
    }
}

// ---------------------------------------------------------------------------
// d_out = P0 + P1 (fp32, float4)
// ---------------------------------------------------------------------------
__global__ __launch_bounds__(256) void addk(const float* __restrict__ P0,
                                            const float* __restrict__ P1,
                                            float* __restrict__ out) {
  int i = blockIdx.x * blockDim.x + threadIdx.x;  // 2097152 float4s
  f32x4 a = ((const f32x4*)P0)[i];
  f32x4 b = ((const f32x4*)P1)[i];
  ((f32x4*)out)[i] = a + b;
}

// ---------------------------------------------------------------------------
// RMSNorm + RoPE. Q prescaled by D^-0.5 * log2(e) for fixed-max exp2 softmax.
// ---------------------------------------------------------------------------
__global__ __launch_bounds__(256) void normrope(const bf16* __restrict__ QKVb,
                                                const float* __restrict__ cosb,
                                                const float* __restrict__ sinb,
                                                const float* __restrict__ qw,
                                                const float* __restrict__ kw,
                                                bf16* __restrict__ Qb,
                                                bf16* __restrict__ Kb) {
  const int wid = (blockIdx.x * blockDim.x + threadIdx.x) >> 6;
  const int lane = threadIdx.x & 63;
  const int s = wid / 24;
  const int h = wid % 24;
  const bool isq = (h < 16);
  const int col0 = isq ? h * 128 : 2048 + (h - 16) * 128;
  const float* wt = isq ? qw : kw;

  const bf16* row = QKVb + (size_t)s * 4096 + col0;
  float x1 = (float)row[lane];
  float x2 = (float)row[lane + 64];

  float ss = x1 * x1 + x2 * x2;
#pragma unroll
  for (int m = 32; m >= 1; m >>= 1) ss += __shfl_xor(ss, m, 64);
  float rs = rsqrtf(ss * (1.0f / 128.0f) + 1e-6f);

  float c = cosb[(size_t)s * 128 + lane];
  float sn = sinb[(size_t)s * 128 + lane];
  float xn1 = x1 * rs * wt[lane];
  float xn2 = x2 * rs * wt[lane + 64];
  float o1 = xn1 * c - xn2 * sn;
  float o2 = xn2 * c + xn1 * sn;
  const float scale = isq ? 0.12751652f : 1.0f;  // D^-0.5 * log2(e)
  o1 *= scale; o2 *= scale;

  bf16* dst = isq ? (Qb + ((size_t)h * 4096 + s) * 128)
                  : (Kb + ((size_t)(h - 16) * 4096 + s) * 128);
  dst[lane] = (bf16)o1;
  dst[lane + 64] = (bf16)o2;
}

// ---------------------------------------------------------------------------
// V transpose + in-tile permute: Vtp[kvh][d][t*64 + kp] = V[t*64 + sig(kp)][d]
// with sig(kp) = (kp&3)*16 + (kp>>2). Matches attention's P layout kp=l15*4+c.
// ---------------------------------------------------------------------------
__global__ __launch_bounds__(256) void vtrans(const bf16* __restrict__ QKVb,
                                              bf16* __restrict__ Vtp) {
  __shared__ __align__(16) bf16 T[64 * 136];
  const int kvh = blockIdx.y;
  const int s0 = blockIdx.x * 64;
  const int tid = threadIdx.x;
  for (int g = tid; g < 1024; g += 256) {
    int s = g >> 4, cg = g & 15;
    *(bf16x8*)(T + s * 136 + cg * 8) =
        *(const bf16x8*)(QKVb + (size_t)(s0 + s) * 4096 + 3072 + kvh * 128 + cg * 8);
  }
  __syncthreads();
  for (int g = tid; g < 1024; g += 256) {
    int d = g >> 3, sg = g & 7;
    bf16x8 v;
#pragma unroll
    for (int j = 0; j < 8; j++) {
      int kp = sg * 8 + j;
      int s = (kp & 3) * 16 + (kp >> 2);
      v[j] = T[s * 136 + d];
    }
    *(bf16x8*)(Vtp + ((size_t)kvh * 128 + d) * 4096 + s0 + sg * 8) = v;
  }
}

// ---------------------------------------------------------------------------
// Sliding-window GQA flash attention, 2 heads per block.
// Grid 256 (kvh = id&7 XCD swizzle), block = 512 thr = 8 waves:
// wave w -> head gq = w>>2, q-range qw0 = qb0 + (w&3)*32. Both q-heads of one
// KV head share the K/V staging (halves staging bytes + FETCH per MFMA).
// K/V double-buffered in LDS: stage kt+1 while computing kt so the
// global_load_lds drain overlaps compute (1 block/CU -> no sibling to hide it).
// Fixed-max exp2 softmax; per-wave P round-trip (kp = l15*4+c permuted order).
// ---------------------------------------------------------------------------
__global__ __launch_bounds__(512, 2) void attn_kernel(const bf16* __restrict__ Qb,
                                                      const bf16* __restrict__ Kb,
                                                      const bf16* __restrict__ Vtp,
                                                      bf16* __restrict__ Ob) {
  const int SEQ = 4096, W = 1024;
  const float MP = 17.312340f;  // 12 * log2(e)
  __shared__ __align__(16) bf16 Ks[2][64 * 128];
  __shared__ __align__(16) bf16 Vs[2][128 * 64];
  __shared__ __align__(16) bf16 Ps[8][32 * 64];

  const int id = blockIdx.x;
  const int kvh = id & 7;
  const int qb0 = (id >> 3) * 128;
  const int tid = threadIdx.x, w = tid >> 6, lane = tid & 63;
  const int l15 = lane & 15, quad = lane >> 4;
  const int gq = w >> 2, h = kvh * 2 + gq;
  const int qw0 = qb0 + (w & 3) * 32;

  // Q fragments in registers: A-layout (m-row = l15, k = quad*8+j)
  bf16x8 qf[2][4];
#pragma unroll
  for (int m = 0; m < 2; m++) {
    const bf16* qp = Qb + ((size_t)h * SEQ + qw0 + m * 16 + l15) * 128 + quad * 8;
#pragma unroll
    for (int kb = 0; kb < 4; kb++) qf[m][kb] = *(const bf16x8*)(qp + kb * 32);
  }

  f32x4 o[2][8] = {};
  f32x4 lr[2] = {};
  bf16* pw = &Ps[w][0];
  const bf16* kbase = Kb + (size_t)kvh * SEQ * 128;
  const bf16* vbase = Vtp + (size_t)kvh * 128 * SEQ;

  int jmin = qb0 - (W - 1); if (jmin < 0) jmin = 0;
  const int kt0 = jmin >> 6, kt1 = (qb0 + 127) >> 6;

  // --- staging helper (512 threads: 2 granule-slots each for K and V) ---
#define STAGE_KV(KT, BUF)                                                       \
  {                                                                             \
    const int k0s = (KT) * 64;                                                  \
    _Pragma("unroll")                                                           \
    for (int i = 0; i < 2; i++) {                                               \
      int slot = i * 512 + tid;                                                 \
      int key = slot >> 4, gg = slot & 15;                                      \
      int gsw = gg ^ (key & 7);                                                 \
      gload_lds16(kbase + (size_t)(k0s + key) * 128 + gsw * 8,                  \
                  Ks[BUF] + (i * 512 + w * 64) * 8);                            \
    }                                                                           \
    _Pragma("unroll")                                                           \
    for (int i = 0; i < 2; i++) {                                               \
      int slot = i * 512 + tid;                                                 \
      int d = slot >> 3, gg = slot & 7;                                         \
      int gsw = gg ^ (d & 7);                                                   \
      gload_lds16(vbase + (size_t)d * SEQ + k0s + gsw * 8,                      \
                  Vs[BUF] + (i * 512 + w * 64) * 8);                            \
    }                                                                           \
  }

  STAGE_KV(kt0, 0);
  __syncthreads();

  for (int kt = kt0; kt <= kt1; ++kt) {
    const int buf = kt & 1;
    if (kt + 1 <= kt1) STAGE_KV(kt + 1, buf ^ 1);  // prefetch next tile

    const int k0 = kt * 64;
    const bool alive = (k0 <= qw0 + 31) && (k0 + 63 > qw0 - W);
    if (alive) {
      const bool full = (k0 + 63 <= qw0) && (k0 > qw0 + 31 - W);
      const bf16* ksb = Ks[buf];
      const bf16* vsb = Vs[buf];
      // QK^T: s[m][c] covers q = qw0+m*16+quad*4+r, key = k0+c*16+l15
      f32x4 s[2][4] = {};
#pragma unroll
      for (int c = 0; c < 4; c++) {
        const int key = c * 16 + l15;
        bf16x8 kf[4];
#pragma unroll
        for (int kb = 0; kb < 4; kb++)
          kf[kb] = *(const bf16x8*)(ksb + key * 128 + (((kb * 4 + quad) ^ (key & 7)) << 3));
#pragma unroll
        for (int kb = 0; kb < 4; kb++) {
          s[0][c] = MFMA16(qf[0][kb], kf[kb], s[0][c]);
          s[1][c] = MFMA16(qf[1][kb], kf[kb], s[1][c]);
        }
      }
      // exp2 (fixed max), accumulate l, pack P (kp = l15*4 + c) as b64 stores
#pragma unroll
      for (int m = 0; m < 2; m++)
#pragma unroll
        for (int r = 0; r < 4; r++) {
          float p[4];
          if (full) {
#pragma unroll
            for (int c = 0; c < 4; c++) p[c] = __builtin_amdgcn_exp2f(s[m][c][r] - MP);
          } else {
            const int i_ = qw0 + m * 16 + quad * 4 + r;
#pragma unroll
            for (int c = 0; c < 4; c++) {
              int j = k0 + c * 16 + l15;
              p[c] = (j <= i_ && j > i_ - W) ? __builtin_amdgcn_exp2f(s[m][c][r] - MP) : 0.0f;
            }
          }
          lr[m][r] += p[0] + p[1] + p[2] + p[3];
          bf16x4 pk;
          pk[0] = (bf16)p[0]; pk[1] = (bf16)p[1]; pk[2] = (bf16)p[2]; pk[3] = (bf16)p[3];
          const int q = m * 16 + quad * 4 + r;
          *(bf16x4*)(pw + q * 64 + (((l15 >> 1) ^ (q & 7)) << 3) + (l15 & 1) * 4) = pk;
        }
      asm volatile("s_waitcnt lgkmcnt(0)" ::: "memory");
      // P A-frags (row = m*16+l15, kp = kb*32+quad*8) and PV
      bf16x8 pf[2][2];
#pragma unroll
      for (int m = 0; m < 2; m++)
#pragma unroll
        for (int kb = 0; kb < 2; kb++)
          pf[m][kb] = *(const bf16x8*)(pw + (m * 16 + l15) * 64 +
                                       (((kb * 4 + quad) ^ (l15 & 7)) << 3));
#pragma unroll
      for (int n = 0; n < 8; n++) {
        const int d = n * 16 + l15;
        bf16x8 vf0 = *(const bf16x8*)(vsb + d * 64 + ((quad ^ (l15 & 7)) << 3));
        bf16x8 vf1 = *(const bf16x8*)(vsb + d * 64 + (((4 + quad) ^ (l15 & 7)) << 3));
        o[0][n] = MFMA16(pf[0][0], vf0, o[0][n]);
        o[0][n] = MFMA16(pf[0][1], vf1, o[0][n]);
        o[1][n] = MFMA16(pf[1][0], vf0, o[1][n]);
        o[1][n] = MFMA16(pf[1][1], vf1, o[1][n]);
      }
    }
    __syncthreads();  // publishes prefetch (vmcnt drain overlapped compute)
  }

  float linv[2][4];
#pragma unroll
  for (int m = 0; m < 2; m++)
#pragma unroll
    for (int r = 0; r < 4; r++) {
      float v = lr[m][r];
      v += __shfl_xor(v, 1, 64);
      v += __shfl_xor(v, 2, 64);
      v += __shfl_xor(v, 4, 64);
      v += __shfl_xor(v, 8, 64);
      linv[m][r] = 1.0f / v;
    }
#pragma unroll
  for (int m = 0; m < 2; m++)
#pragma unroll
    for (int n = 0; n < 8; n++)
#pragma unroll
      for (int r = 0; r < 4; r++) {
        int i_ = qw0 + m * 16 + quad * 4 + r;
        Ob[(size_t)i_ * 2048 + h * 128 + n * 16 + l15] = (bf16)(o[m][n][r] * linv[m][r]);
      }
#undef STAGE_KV
}

// ---------------------------------------------------------------------------
// Orchestration
// ---------------------------------------------------------------------------
extern "C" void kernel_launch(void* const* d_in, const int* in_sizes, int n_in,
                              void* d_out, int out_size, void* d_ws, size_t ws_size,
                              hipStream_t stream) {
  const float* hid  = (const float*)d_in[0];
  const float* cosb = (const float*)d_in[1];
  const float* sinb = (const float*)d_in[2];
  const float* Wq   = (const float*)d_in[3];
  const float* Wk   = (const float*)d_in[4];
  const float* Wv   = (const float*)d_in[5];
  const float* Wo   = (const float*)d_in[6];
  const float* qw   = (const float*)d_in[7];
  const float* kw   = (const float*)d_in[8];

  if (ws_size < (size_t)(112u) * 1024u * 1024u) return;

  char* ws = (char*)d_ws;
  bf16* Xbf  = (bf16*)(ws);                 // 4096x2048 (16 MB)
  bf16* Vtp  = (bf16*)(ws);                 //   Vtp reuses Xbf slot after gemm1 (8 MB)
  float* P0  = (float*)(ws);                //   P0 reuses [0,32M) after attn (32 MB)
  bf16* Wcat = (bf16*)(ws + (16u << 20));   // [Wq;Wk;Wv] 4096x2048 (16 MB)
  bf16* Wob  = (bf16*)(ws + (32u << 20));   // 2048x2048 (8 MB)
  bf16* QKVb = (bf16*)(ws + (40u << 20));   // 4096x4096 (32 MB)
  float* P1  = (float*)(ws + (40u << 20));  //   P1 reuses QKVb slot after normrope/vtrans
  bf16* Qb   = (bf16*)(ws + (72u << 20));   // [16][4096][128] (16 MB)
  bf16* Kb   = (bf16*)(ws + (88u << 20));   // [8][4096][128] (8 MB)
  bf16* Ob   = (bf16*)(ws + (96u << 20));   // 4096x2048 (16 MB)

  cvt_all<<<20480, 256, 0, stream>>>(hid, Wq, Wk, Wv, Wo, Xbf, Wcat, Wob);

  gemm_bt<bf16><<<dim3(32, 32, 1), 256, 0, stream>>>(Xbf, Wcat, QKVb,
                                                     4096, 4096, 2048, 2048, 0);
  vtrans<<<dim3(64, 8), 256, 0, stream>>>(QKVb, Vtp);
  normrope<<<24576, 256, 0, stream>>>(QKVb, cosb, sinb, qw, kw, Qb, Kb);
  attn_kernel<<<256, 512, 0, stream>>>(Qb, Kb, Vtp, Ob);
  // split-K out-proj: z in {0,1} does K=1024 slice, partials to P0/P1 (fp32)
  gemm_bt<float><<<dim3(16, 32, 2), 256, 0, stream>>>(Ob, Wob, P0,
                                                      4096, 2048, 1024, 2048,
                                                      (size_t)(40u << 20) / 4);
  addk<<<8192, 256, 0, stream>>>(P0, P0 + ((size_t)(40u << 20) / 4), (float*)d_out);
}